// Round 16
// baseline (215.444 us; speedup 1.0000x reference)
//
#include <hip/hip_runtime.h>

// SLAYER constants
#define ALPHA  0.90483741803595952f   /* exp(-1/10)  */
#define ALPHA64 0.0016615572731739337f /* exp(-6.4)  */
#define THETA  10.0f
#define BF1    ((unsigned short)0x3F80) /* 1.0f as bf16 */
#define ISCALE 0.015625f               /* 1/64, exact */
#define ALPHA8  0.44932896411722156f   /* exp(-0.8) */

typedef short   bf16x8 __attribute__((ext_vector_type(8)));
typedef float   f32x4  __attribute__((ext_vector_type(4)));
typedef float   f32x4v __attribute__((ext_vector_type(4)));
typedef unsigned short ushort4v __attribute__((ext_vector_type(4)));
typedef unsigned short ushort8v __attribute__((ext_vector_type(8)));
typedef unsigned char  uchar4v  __attribute__((ext_vector_type(4)));
typedef unsigned char  uchar8v  __attribute__((ext_vector_type(8)));
typedef long long i64;

// RNE float -> bf16 bits
__device__ __forceinline__ unsigned short f2bf(float f) {
    unsigned int x = __float_as_uint(f);
    unsigned int r = (x + 0x7FFFu + ((x >> 16) & 1u)) >> 16;
    return (unsigned short)r;
}
__device__ __forceinline__ float bf2f(unsigned short h) {
    return __uint_as_float(((unsigned int)h) << 16);
}
// 2-way bf16 split: w ~= h0+h1 (residual ~2^-17 rel)
__device__ __forceinline__ void split2(float w, unsigned short& h0,
                                       unsigned short& h1) {
    h0 = f2bf(w);          float r0 = w - bf2f(h0);
    h1 = f2bf(r0);
}
// HW fp8 converts
__device__ __forceinline__ unsigned char f2fp8(float f) {
    int pk = __builtin_amdgcn_cvt_pk_fp8_f32(f, 0.f, 0, false);
    return (unsigned char)(pk & 0xFF);
}
__device__ __forceinline__ float fp82f(unsigned char b) {
    return __builtin_amdgcn_cvt_f32_fp8((int)b, 0);
}

// ---------------------------------------------------------------------------
// prep_scan_pack: fused input prep (scan + DIRECT transposed output) + weight
// packing.
// Blocks 0..639: b = blk/20, c-group g = blk%20 (8 channels, last group 4).
//   Each lane owns 64 t-elements of one channel row:
//     Infp8[row][t] = fp8(x)  (exact),
//     P = psp_t(x) scanned in fp32 (shfl carry), staged bf16 in LDS,
//     written transposed: PT[b][t][c0..c0+8) (c padded to 160 with zeros).
// Blocks 640..1727: weight packing (W1 bf16-split2, W2 fp8-split2,
//   Wl1 fp8-split2 x64, Wl2 bf16-split2).
// ---------------------------------------------------------------------------
__global__ __launch_bounds__(256) void prep_scan_pack(
    const float* __restrict__ In, unsigned char* __restrict__ Infp8,
    unsigned short* __restrict__ PT,
    const float* __restrict__ W1,  const float* __restrict__ W2,
    const float* __restrict__ Wl1, const float* __restrict__ Wl2,
    unsigned short* __restrict__ W1p,  unsigned char* __restrict__ W2p8,
    unsigned char* __restrict__ Wl1p8, unsigned short* __restrict__ Wl2p)
{
    const int blk = blockIdx.x;
    if (blk >= 640) {
        const int bidx = blk - 640;
        if (bidx >= 512 && bidx < 544) {            // W2 -> fp8 split-2
            int m = bidx - 512;
            for (int k = threadIdx.x; k < 512; k += 256) {
                float w = (m < 20) ? W2[(long long)m * 512 + k] : 0.f;
                unsigned char h0 = f2fp8(w);
                unsigned char h1 = f2fp8(w - fp82f(h0));
                W2p8[(long long)m * 512 + k] = h0;
                W2p8[16384 + (long long)m * 512 + k] = h1;
            }
        } else if (bidx >= 544 && bidx < 1056) {    // Wl1 -> fp8 split-2, x64
            int m = bidx - 544;
            for (int k = threadIdx.x; k < 2048; k += 256) {
                float w = Wl1[(long long)m * 2048 + k] * 64.0f;
                unsigned char h0 = f2fp8(w);
                unsigned char h1 = f2fp8(w - fp82f(h0));
                Wl1p8[(long long)m * 2048 + k] = h0;
                Wl1p8[1048576 + (long long)m * 2048 + k] = h1;
            }
        } else {                                    // W1 / Wl2 -> bf16 split-2
            const float* W; unsigned short* P; int M, K, Kp, Mp, m;
            if (bidx < 512) { W = W1;  P = W1p;  M = 512; K = 156; Kp = 160; Mp = 512; m = bidx; }
            else            { W = Wl2; P = Wl2p; M = 20;  K = 512; Kp = 512; Mp = 32;  m = bidx - 1056; }
            for (int k = threadIdx.x; k < Kp; k += 256) {
                float v = (m < M && k < K) ? W[(long long)m * K + k] : 0.f;
                unsigned short h0, h1;
                split2(v, h0, h1);
                P[(long long)m * Kp + k] = h0;
                P[(long long)Mp * Kp + (long long)m * Kp + k] = h1;
            }
        }
        return;
    }

    // ---------------- input scan + direct transpose ----------------
    __shared__ unsigned short Pt[8][2056];   // bf16 tile, padded stride
    const int b  = blk / 20;
    const int g  = blk % 20;
    const int c0 = g * 8;
    const int nRows = (c0 + 8 <= 156) ? 8 : (156 - c0);

    const int tid = threadIdx.x;
    const int g8  = tid >> 5;        // channel within group (0..7)
    const int l   = tid & 31;        // lane within channel (t-segment)
    const bool live = (g8 < nRows);
    const unsigned char ONE8 = f2fp8(1.0f);

    float v[64];
    if (live) {
        const int row = b * 156 + c0 + g8;
        const float* x = In + (long long)row * 2048 + l * 64;
        #pragma unroll
        for (int q = 0; q < 16; ++q)
            *(f32x4v*)&v[q * 4] = *(const f32x4v*)(x + q * 4);

        // raw binary input as fp8 (exact), 64 B contiguous per lane
        unsigned char raw[64];
        #pragma unroll
        for (int k = 0; k < 64; ++k)
            raw[k] = (v[k] >= 0.5f) ? ONE8 : (unsigned char)0;
        unsigned char* dst = Infp8 + (long long)row * 2048 + l * 64;
        #pragma unroll
        for (int q = 0; q < 8; ++q)
            *(uchar8v*)(dst + q * 8) = *(uchar8v*)&raw[q * 8];

        // local inclusive scan of 64 elements
        float y = 0.f;
        #pragma unroll
        for (int k = 0; k < 64; ++k) { y = ALPHA * y + v[k]; v[k] = y; }

        // 32-lane carry propagation (weights ALPHA64^d) via shuffle
        float val = y;
        float m = ALPHA64;
        #pragma unroll
        for (int d = 1; d < 32; d <<= 1) {
            float p = __shfl_up(val, d, 32);
            if (l >= d) val += m * p;
            m *= m;
        }
        float carry = __shfl_up(val, 1, 32);
        if (l == 0) carry = 0.f;

        float ak = ALPHA;
        #pragma unroll
        for (int k = 0; k < 64; ++k) {
            float yk = v[k] + ak * carry;
            ak *= ALPHA;
            Pt[g8][l * 64 + k] = f2bf(yk);
        }
    } else {
        // zero-fill dead channel rows (c >= 156 padding)
        for (int k = l; k < 2048; k += 32) Pt[g8][k] = 0;
    }
    __syncthreads();

    // write transposed: PT[b][t][c0 + 0..8)
    unsigned short* Pb = PT + (long long)b * 327680 + c0;
    #pragma unroll
    for (int it = 0; it < 8; ++it) {
        int t = tid + it * 256;
        unsigned short r[8];
        #pragma unroll
        for (int c = 0; c < 8; ++c) r[c] = Pt[c][t];
        *(ushort8v*)(Pb + (long long)t * 160) = *(ushort8v*)r;
    }
}

// ---------------------------------------------------------------------------
// MEGA1: blocks [0,2048)  = branch-1 GEMM1 (bf16 MFMA, fused threshold,
//                           bit-packed spike output)
//        blocks [2048,3328) = branch-2 GEMM1 (fp8 MFMA, split-K x4), laid out
//                           n + 40*(m + 8*ks) to preserve XCD mod-8 reuse.
// ---------------------------------------------------------------------------
__global__ __launch_bounds__(256) void mega_gemm1(
    const unsigned short* __restrict__ W1p,
    const unsigned short* __restrict__ PT,
    unsigned short* __restrict__ S1bits,     // [32][512][128]
    const unsigned char* __restrict__ Wl1p8, // [2][512][2048] fp8
    const unsigned char* __restrict__ Infp8, // [4992][2048] fp8
    unsigned short* __restrict__ Zp)         // [4][156][16384] c-major bf16
{
    __shared__ alignas(16) unsigned char SMEM[30720];
    const int bx  = blockIdx.x;
    const int tid = threadIdx.x;
    const int lane = tid & 63, w = tid >> 6;
    const int wy = w >> 1, wx = w & 1;
    const int l15 = lane & 15, kq = lane >> 4;

    if (bx < 2048) {
        // ================= branch-1 GEMM1 =================
        auto As = (unsigned short (*)[128][40])SMEM;       // [2][128][40]
        auto Bs = (unsigned short (*)[40])(SMEM + 20480);  // [128][40]

        const int z  = bx >> 6;
        const int m0 = ((bx >> 4) & 3) * 128;
        const int n0 = (bx & 15) * 128;
        const unsigned short* Tb = PT + (long long)z * 327680;

        int aPl[4], aM[4], aK8[4];
        #pragma unroll
        for (int s = 0; s < 4; ++s) {
            int id = tid + s * 256;
            aPl[s] = id >> 9; int rem = id & 511;
            aM[s] = rem >> 2; aK8[s] = (rem & 3) * 8;
        }
        int bT[2], bC8[2];
        #pragma unroll
        for (int s = 0; s < 2; ++s) {
            int id = tid + s * 256;
            bT[s] = id >> 2; bC8[s] = (id & 3) * 8;
        }

        f32x4 acc[4][4] = {};
        ushort8v aReg[4], bReg[2];

        #pragma unroll
        for (int s = 0; s < 4; ++s)
            aReg[s] = *(const ushort8v*)(W1p + (long long)aPl[s] * 81920 +
                                         (long long)(m0 + aM[s]) * 160 + aK8[s]);
        #pragma unroll
        for (int s = 0; s < 2; ++s)
            bReg[s] = *(const ushort8v*)(Tb + (long long)(n0 + bT[s]) * 160 + bC8[s]);
        #pragma unroll
        for (int s = 0; s < 4; ++s) *(ushort8v*)&As[aPl[s]][aM[s]][aK8[s]] = aReg[s];
        #pragma unroll
        for (int s = 0; s < 2; ++s) *(ushort8v*)&Bs[bT[s]][bC8[s]] = bReg[s];
        __syncthreads();

        #pragma unroll
        for (int it = 0; it < 5; ++it) {
            const int kn = (it + 1) * 32;
            if (it < 4) {
                #pragma unroll
                for (int s = 0; s < 4; ++s)
                    aReg[s] = *(const ushort8v*)(W1p + (long long)aPl[s] * 81920 +
                                                 (long long)(m0 + aM[s]) * 160 + kn + aK8[s]);
                #pragma unroll
                for (int s = 0; s < 2; ++s)
                    bReg[s] = *(const ushort8v*)(Tb + (long long)(n0 + bT[s]) * 160 + kn + bC8[s]);
            }

            bf16x8 bfr[4];
            #pragma unroll
            for (int nt = 0; nt < 4; ++nt)
                bfr[nt] = *(const bf16x8*)&Bs[wx * 64 + nt * 16 + l15][kq * 8];
            #pragma unroll
            for (int s = 0; s < 2; ++s) {
                #pragma unroll
                for (int mt = 0; mt < 4; ++mt) {
                    bf16x8 afr = *(const bf16x8*)&As[s][wy * 64 + mt * 16 + l15][kq * 8];
                    #pragma unroll
                    for (int nt = 0; nt < 4; ++nt)
                        acc[mt][nt] = __builtin_amdgcn_mfma_f32_16x16x32_bf16(
                            afr, bfr[nt], acc[mt][nt], 0, 0, 0);
                }
            }
            __syncthreads();
            if (it < 4) {
                #pragma unroll
                for (int s = 0; s < 4; ++s) *(ushort8v*)&As[aPl[s]][aM[s]][aK8[s]] = aReg[s];
                #pragma unroll
                for (int s = 0; s < 2; ++s) *(ushort8v*)&Bs[bT[s]][bC8[s]] = bReg[s];
                __syncthreads();
            }
        }

        unsigned short* Db = S1bits + (long long)z * 512 * 128;
        #pragma unroll
        for (int mt = 0; mt < 4; ++mt) {
            #pragma unroll
            for (int i = 0; i < 4; ++i) {
                int m = m0 + wy * 64 + mt * 16 + kq * 4 + i;
                #pragma unroll
                for (int nt = 0; nt < 4; ++nt) {
                    unsigned long long mask = __ballot(acc[mt][nt][i] >= THETA);
                    if (l15 == 0) {
                        int nchunk = (n0 + wx * 64 + nt * 16) >> 4;
                        Db[(long long)m * 128 + nchunk] =
                            (unsigned short)((mask >> (kq * 16)) & 0xFFFFu);
                    }
                }
            }
        }
    } else {
        // ================= branch-2 GEMM1 (fp8) =================
        auto As8 = (unsigned char (*)[64][72])SMEM;        // [2][64][72]
        auto Bs8 = (unsigned char (*)[72])(SMEM + 9216);   // [128][72]

        const int id0 = bx - 2048;
        const int nIdx = id0 % 40;
        if (nIdx >= 39) return;
        const int rest = id0 / 40;
        const int n0  = nIdx * 128;
        const int m0  = (rest & 7) * 64;
        const int ksl = rest >> 3;
        const int ks0 = ksl * 512;

        int aPl[4], aM[4], aK8[4];
        #pragma unroll
        for (int s = 0; s < 4; ++s) {
            int id = tid + s * 256;
            aPl[s] = id >> 9; int rem = id & 511;
            aM[s] = rem >> 3; aK8[s] = (rem & 7) * 8;
        }
        int bN[4], bK8[4];
        #pragma unroll
        for (int s = 0; s < 4; ++s) {
            int id = tid + s * 256;
            bN[s] = id >> 3; bK8[s] = (id & 7) * 8;
        }

        f32x4 acc[2][4] = {};
        uchar8v aReg[4], bReg[4];

        #pragma unroll
        for (int s = 0; s < 4; ++s)
            aReg[s] = *(const uchar8v*)(Wl1p8 + (long long)aPl[s] * 1048576 +
                                        (long long)(m0 + aM[s]) * 2048 + ks0 + aK8[s]);
        #pragma unroll
        for (int s = 0; s < 4; ++s)
            bReg[s] = *(const uchar8v*)(Infp8 + (long long)(n0 + bN[s]) * 2048 + ks0 + bK8[s]);
        #pragma unroll
        for (int s = 0; s < 4; ++s) *(uchar8v*)&As8[aPl[s]][aM[s]][aK8[s]] = aReg[s];
        #pragma unroll
        for (int s = 0; s < 4; ++s) *(uchar8v*)&Bs8[bN[s]][bK8[s]] = bReg[s];
        __syncthreads();

        for (int it = 0; it < 8; ++it) {
            const int kn = ks0 + (it + 1) * 64;
            if (it < 7) {
                #pragma unroll
                for (int s = 0; s < 4; ++s)
                    aReg[s] = *(const uchar8v*)(Wl1p8 + (long long)aPl[s] * 1048576 +
                                                (long long)(m0 + aM[s]) * 2048 + kn + aK8[s]);
                #pragma unroll
                for (int s = 0; s < 4; ++s)
                    bReg[s] = *(const uchar8v*)(Infp8 + (long long)(n0 + bN[s]) * 2048 + kn + bK8[s]);
            }

            #pragma unroll
            for (int ks = 0; ks < 2; ++ks) {
                i64 bfr[4];
                #pragma unroll
                for (int nt = 0; nt < 4; ++nt)
                    bfr[nt] = *(const i64*)&Bs8[wx * 64 + nt * 16 + l15][ks * 32 + kq * 8];
                #pragma unroll
                for (int s = 0; s < 2; ++s) {
                    #pragma unroll
                    for (int mt = 0; mt < 2; ++mt) {
                        i64 afr = *(const i64*)&As8[s][wy * 32 + mt * 16 + l15][ks * 32 + kq * 8];
                        #pragma unroll
                        for (int nt = 0; nt < 4; ++nt)
                            acc[mt][nt] = __builtin_amdgcn_mfma_f32_16x16x32_fp8_fp8(
                                afr, bfr[nt], acc[mt][nt], 0, 0, 0);
                    }
                }
            }
            __syncthreads();
            if (it < 7) {
                #pragma unroll
                for (int s = 0; s < 4; ++s) *(uchar8v*)&As8[aPl[s]][aM[s]][aK8[s]] = aReg[s];
                #pragma unroll
                for (int s = 0; s < 4; ++s) *(uchar8v*)&Bs8[bN[s]][bK8[s]] = bReg[s];
                __syncthreads();
            }
        }

        unsigned short* Tu = (unsigned short*)SMEM;
        #pragma unroll
        for (int mt = 0; mt < 2; ++mt) {
            #pragma unroll
            for (int i = 0; i < 4; ++i) {
                int mL = wy * 32 + mt * 16 + kq * 4 + i;
                #pragma unroll
                for (int nt = 0; nt < 4; ++nt) {
                    int nL = wx * 64 + nt * 16 + l15;
                    Tu[mL * 129 + nL] = f2bf(acc[mt][nt][i] * ISCALE);
                }
            }
        }
        __syncthreads();

        unsigned short* Zs = Zp + (long long)ksl * 2555904;
        #pragma unroll
        for (int s2 = 0; s2 < 32; ++s2) {
            int id = tid + s2 * 256;
            int cL = id >> 6;
            int mL = id & 63;
            int n = n0 + cL;
            int bb = n / 156, cc = n - bb * 156;
            Zs[(long long)cc * 16384 + bb * 512 + m0 + mL] = Tu[mL * 129 + cL];
        }
    }
}

// ---------------------------------------------------------------------------
// MEGA2: blocks [0,1024)    = branch-1 GEMM2 (fp8 MFMA, split-K x2, bit-
//                             expanded B)
//        blocks [1024,1536) = branch-2 scan_sum4_perm (32 rows/block)
// ---------------------------------------------------------------------------
__global__ __launch_bounds__(256) void mega_stage2(
    const unsigned char* __restrict__ W2p8,
    const unsigned short* __restrict__ S1bits,
    float* __restrict__ C2p,
    const unsigned short* __restrict__ Zp,
    const int* __restrict__ perm,
    unsigned short* __restrict__ L1T)
{
    __shared__ alignas(16) unsigned char SMEM[20608];
    const int bx  = blockIdx.x;
    const int tid = threadIdx.x;

    if (bx < 1024) {
        auto As = (unsigned char (*)[32][72])SMEM;        // [2][32][72]
        auto Bs = (unsigned char (*)[72])(SMEM + 4608);   // [128][72]

        const int lane = tid & 63, w = tid >> 6;
        const int l15 = lane & 15, kq = lane >> 4;
        const int n0  = (bx & 15) * 128;
        const int ksl = (bx >> 4) & 1;
        const int b   = bx >> 5;
        const int ks0 = ksl * 256;

        const unsigned short* Bb = S1bits + (long long)b * 512 * 128;
        const unsigned char ONE8 = f2fp8(1.0f);

        int aPl[2], aM[2], aK8[2];
        #pragma unroll
        for (int s = 0; s < 2; ++s) {
            int id = tid + s * 256;
            aPl[s] = id >> 8; int rem = id & 255;
            aM[s] = rem >> 3; aK8[s] = (rem & 7) * 8;
        }
        const int kb = (tid >> 4) * 4;
        const int nb = (tid & 15) * 8;
        const int nchunk = (n0 + nb) >> 4;
        const int nshift = nb & 15;

        f32x4 acc[2][2] = {};
        uchar8v aReg[2];
        unsigned short bBits[4];

        auto loadA = [&](int k0) {
            #pragma unroll
            for (int s = 0; s < 2; ++s)
                aReg[s] = *(const uchar8v*)(W2p8 + (long long)aPl[s] * 16384 +
                                            (long long)aM[s] * 512 + k0 + aK8[s]);
        };
        auto loadB = [&](int k0) {
            #pragma unroll
            for (int kk2 = 0; kk2 < 4; ++kk2)
                bBits[kk2] = Bb[(long long)(k0 + kb + kk2) * 128 + nchunk];
        };
        auto stage = [&]() {
            #pragma unroll
            for (int s = 0; s < 2; ++s) *(uchar8v*)&As[aPl[s]][aM[s]][aK8[s]] = aReg[s];
            unsigned char bv[4][8];
            #pragma unroll
            for (int kk2 = 0; kk2 < 4; ++kk2) {
                unsigned int bits = ((unsigned int)bBits[kk2] >> nshift) & 0xFFu;
                #pragma unroll
                for (int j = 0; j < 8; ++j)
                    bv[kk2][j] = ((bits >> j) & 1u) ? ONE8 : (unsigned char)0;
            }
            #pragma unroll
            for (int j = 0; j < 8; ++j) {
                uchar4v v4 = { bv[0][j], bv[1][j], bv[2][j], bv[3][j] };
                *(uchar4v*)&Bs[nb + j][kb] = v4;
            }
        };

        loadA(ks0); loadB(ks0);
        stage();
        __syncthreads();

        #pragma unroll
        for (int it = 0; it < 4; ++it) {
            const int kn = ks0 + (it + 1) * 64;
            if (it < 3) { loadA(kn); loadB(kn); }

            #pragma unroll
            for (int ks = 0; ks < 2; ++ks) {
                i64 bfr[2];
                #pragma unroll
                for (int nt = 0; nt < 2; ++nt)
                    bfr[nt] = *(const i64*)&Bs[w * 32 + nt * 16 + l15][ks * 32 + kq * 8];
                #pragma unroll
                for (int s = 0; s < 2; ++s) {
                    #pragma unroll
                    for (int mt = 0; mt < 2; ++mt) {
                        i64 afr = *(const i64*)&As[s][mt * 16 + l15][ks * 32 + kq * 8];
                        #pragma unroll
                        for (int nt = 0; nt < 2; ++nt)
                            acc[mt][nt] = __builtin_amdgcn_mfma_f32_16x16x32_fp8_fp8(
                                afr, bfr[nt], acc[mt][nt], 0, 0, 0);
                    }
                }
            }
            __syncthreads();
            if (it < 3) {
                stage();
                __syncthreads();
            }
        }

        float* Cb = C2p + (long long)b * 20 * 2048 + (long long)ksl * 1310720LL;
        #pragma unroll
        for (int mt = 0; mt < 2; ++mt) {
            #pragma unroll
            for (int i = 0; i < 4; ++i) {
                int m = mt * 16 + kq * 4 + i;
                if (m >= 20) continue;
                #pragma unroll
                for (int nt = 0; nt < 2; ++nt) {
                    int n = n0 + w * 32 + nt * 16 + l15;
                    Cb[(long long)m * 2048 + n] = acc[mt][nt][i];
                }
            }
        }
    } else {
        auto Xs = (float (*)[32])SMEM;              // [156][32]
        int* p  = (int*)(SMEM + 19968);             // [156]

        const int r0 = (bx - 1024) * 32;
        for (int i = tid; i < 156; i += 256) p[i] = perm[i];

        const int row = tid & 31;
        const int cq  = tid >> 5;
        #pragma unroll
        for (int it = 0; it < 20; ++it) {
            int c = it * 8 + cq;
            if (c < 156) {
                long long base = (long long)c * 16384 + r0 + row;
                float s = bf2f(Zp[base]) + bf2f(Zp[base + 2555904]) +
                          bf2f(Zp[base + 2 * 2555904]) + bf2f(Zp[base + 3 * 2555904]);
                Xs[c][row] = s;
            }
        }
        __syncthreads();

        if (tid < 32) {
            float y = 0.f;
            for (int c = 0; c < 156; ++c) {
                y = ALPHA * y + Xs[p[c]][tid];
                L1T[(long long)c * 16384 + r0 + tid] = (y >= THETA) ? BF1 : 0;
            }
        }
    }
}

// ---------------------------------------------------------------------------
// MEGA3: blocks [0,640)   = branch-1 final T-scan (sum 2 partials -> spikes)
//        blocks [640,704) = branch-2 GEMM2 (bf16 MFMA)
// ---------------------------------------------------------------------------
__global__ __launch_bounds__(256) void mega_stage3(
    const float* __restrict__ C2p, float* __restrict__ out,
    const unsigned short* __restrict__ Wl2p,
    const unsigned short* __restrict__ L1T,
    float* __restrict__ Cl2)
{
    __shared__ alignas(16) unsigned char SMEM[27648];
    const int bx  = blockIdx.x;
    const int tid = threadIdx.x;

    if (bx < 640) {
        float* sc = (float*)SMEM;
        const int row = bx;
        const float* x = C2p + (long long)row * 2048 + tid * 8;

        float v[8];
        #pragma unroll
        for (int k = 0; k < 8; ++k) v[k] = x[k] + x[k + 1310720LL];

        float y = 0.f;
        #pragma unroll
        for (int k = 0; k < 8; ++k) { y = ALPHA * y + v[k]; v[k] = y; }

        float val = y;
        sc[tid] = val;
        float m = ALPHA8;
        for (int d = 1; d < 256; d <<= 1) {
            __syncthreads();
            float p = (tid >= d) ? sc[tid - d] : 0.f;
            __syncthreads();
            val += m * p;
            sc[tid] = val;
            m *= m;
        }
        __syncthreads();
        float carry = (tid > 0) ? sc[tid - 1] : 0.f;

        float* o = out + (long long)row * 2204 + tid * 8;
        float ak = ALPHA;
        #pragma unroll
        for (int k = 0; k < 8; ++k) {
            float yk = v[k] + ak * carry;
            ak *= ALPHA;
            o[k] = (yk >= THETA) ? 1.0f : 0.0f;
        }
    } else {
        auto As = (unsigned short (*)[32][72])SMEM;         // [2][32][72]
        auto Bs = (unsigned short (*)[72])(SMEM + 9216);    // [128][72]

        const int id2 = bx - 640;
        const int n0 = (id2 & 1) * 128;
        const int b  = id2 >> 1;
        const int lane = tid & 63, w = tid >> 6;
        const int l15 = lane & 15, kq = lane >> 4;

        f32x4 acc[2][2] = {};

        for (int k0 = 0; k0 < 512; k0 += 64) {
            #pragma unroll
            for (int s = 0; s < 2; ++s) {
                int id = tid + s * 256;
                int pl = id >> 8, rem = id & 255;
                int m = rem >> 3, k8 = (rem & 7) * 8;
                ushort8v v = *(const ushort8v*)(Wl2p + (long long)pl * 16384 +
                                                (long long)m * 512 + k0 + k8);
                *(ushort8v*)&As[pl][m][k8] = v;
            }
            #pragma unroll
            for (int s = 0; s < 4; ++s) {
                int id = tid + s * 256;
                int n = id >> 3, k8 = (id & 7) * 8;
                ushort8v v = {0,0,0,0,0,0,0,0};
                if (n0 + n < 156)
                    v = *(const ushort8v*)(L1T + (long long)(n0 + n) * 16384 +
                                           b * 512 + k0 + k8);
                *(ushort8v*)&Bs[n][k8] = v;
            }
            __syncthreads();

            #pragma unroll
            for (int ks = 0; ks < 2; ++ks) {
                bf16x8 bfr[2];
                #pragma unroll
                for (int nt = 0; nt < 2; ++nt)
                    bfr[nt] = *(const bf16x8*)&Bs[w * 32 + nt * 16 + l15][ks * 32 + kq * 8];
                #pragma unroll
                for (int s = 0; s < 2; ++s) {
                    #pragma unroll
                    for (int mt = 0; mt < 2; ++mt) {
                        bf16x8 afr = *(const bf16x8*)&As[s][mt * 16 + l15][ks * 32 + kq * 8];
                        #pragma unroll
                        for (int nt = 0; nt < 2; ++nt)
                            acc[mt][nt] = __builtin_amdgcn_mfma_f32_16x16x32_bf16(
                                afr, bfr[nt], acc[mt][nt], 0, 0, 0);
                    }
                }
            }
            __syncthreads();
        }

        float* Cb = Cl2 + (long long)b * 20 * 156;
        #pragma unroll
        for (int mt = 0; mt < 2; ++mt) {
            #pragma unroll
            for (int i = 0; i < 4; ++i) {
                int m = mt * 16 + kq * 4 + i;
                if (m >= 20) continue;
                #pragma unroll
                for (int nt = 0; nt < 2; ++nt) {
                    int n = n0 + w * 32 + nt * 16 + l15;
                    if (n < 156) Cb[(long long)m * 156 + n] = acc[mt][nt][i];
                }
            }
        }
    }
}

// ---------------------------------------------------------------------------
// Final branch-2 output scan (length 156 per row, 640 rows).
// ---------------------------------------------------------------------------
__global__ __launch_bounds__(256) void scan_spike_C_out(
    const float* __restrict__ in, float* __restrict__ out, int rows)
{
    int row = blockIdx.x * blockDim.x + threadIdx.x;
    if (row >= rows) return;
    const float* x = in + (long long)row * 156;
    float* o = out + (long long)row * 2204 + 2048;
    float y = 0.f;
    for (int c = 0; c < 156; ++c) {
        y = ALPHA * y + x[c];
        o[c] = (y >= THETA) ? 1.0f : 0.0f;
    }
}

// ---------------------------------------------------------------------------
// B=32, C_IN=156, T=2048, HID=512, OUT=20. Output [32,20,2204].
// ---------------------------------------------------------------------------
extern "C" void kernel_launch(void* const* d_in, const int* in_sizes, int n_in,
                              void* d_out, int out_size, void* d_ws, size_t ws_size,
                              hipStream_t stream)
{
    const float* In  = (const float*)d_in[0];  // [32][156][2048]
    const float* W1  = (const float*)d_in[1];  // [512][156]
    const float* W2  = (const float*)d_in[2];  // [20][512]
    const float* Wl1 = (const float*)d_in[3];  // [512][2048]
    const float* Wl2 = (const float*)d_in[4];  // [20][512]
    const int*  perm = (const int*)d_in[5];    // [156]
    float* out = (float*)d_out;                // [32][20][2204]

    float* ws = (float*)d_ws;
    // Disjoint layout (float offsets; ws is 256 MiB):
    unsigned short* S1bits = (unsigned short*)ws;              // [32][512][128]
    float* C2p = ws + 1048576LL;                               // [2][32][20][2048]
    unsigned char*  Infp8 = (unsigned char*)(ws + 3670016LL);  // [4992][2048] fp8
    unsigned short* PT   = (unsigned short*)(ws + 11337728LL); // [32][2048][160]
    unsigned short* W1p  = (unsigned short*)(ws + 16580608LL); // [2][512][160]
    unsigned char*  W2p8 = (unsigned char*)(ws + 16662528LL);  // [2][32][512] fp8
    unsigned char*  Wl1p8= (unsigned char*)(ws + 16670720LL);  // [2][512][2048] fp8
    unsigned short* Wl2p = (unsigned short*)(ws + 17195008LL); // [2][32][512]
    unsigned short* Zpbf = (unsigned short*)(ws + 17211392LL); // [4][156][16384] bf16
    unsigned short* L1T  = (unsigned short*)(ws + 22323200LL); // [156][16384]
    float* Cl2 = ws + 23601152LL;                              // [32][20][156]

    dim3 blk(256);

    // ---- Preprocess: fused scan + DIRECT transpose + weight packing ----
    prep_scan_pack<<<dim3(1728), blk, 0, stream>>>(
        In, Infp8, PT, W1, W2, Wl1, Wl2, W1p, W2p8, Wl1p8, Wl2p);

    // ---- Stage 1: both branch GEMM1s in one launch ----
    mega_gemm1<<<dim3(3328), blk, 0, stream>>>(W1p, PT, S1bits,
                                               Wl1p8, Infp8, Zpbf);
    // ---- Stage 2: branch-1 GEMM2 + branch-2 perm-scan ----
    mega_stage2<<<dim3(1536), blk, 0, stream>>>(W2p8, S1bits, C2p,
                                                Zpbf, perm, L1T);
    // ---- Stage 3: branch-1 final scan + branch-2 GEMM2 ----
    mega_stage3<<<dim3(704), blk, 0, stream>>>(C2p, out, Wl2p, L1T, Cl2);
    // ---- Branch-2 output scan ----
    scan_spike_C_out<<<dim3(3), blk, 0, stream>>>(Cl2, out, 640);

    (void)in_sizes; (void)n_in; (void)out_size; (void)ws_size;
}

// Round 17
// 205.192 us; speedup vs baseline: 1.0500x; 1.0500x over previous
//
#include <hip/hip_runtime.h>

// SLAYER constants
#define ALPHA  0.90483741803595952f   /* exp(-1/10) */
#define ALPHA8 0.44932896411722156f   /* exp(-0.8)  */
#define THETA  10.0f
#define BF1    ((unsigned short)0x3F80) /* 1.0f as bf16 */
#define ISCALE 0.015625f               /* 1/64, exact */

typedef short   bf16x8 __attribute__((ext_vector_type(8)));
typedef float   f32x4  __attribute__((ext_vector_type(4)));
typedef float   f32x4v __attribute__((ext_vector_type(4)));
typedef unsigned short ushort4v __attribute__((ext_vector_type(4)));
typedef unsigned short ushort8v __attribute__((ext_vector_type(8)));
typedef unsigned char  uchar4v  __attribute__((ext_vector_type(4)));
typedef unsigned char  uchar8v  __attribute__((ext_vector_type(8)));
typedef long long i64;

// RNE float -> bf16 bits
__device__ __forceinline__ unsigned short f2bf(float f) {
    unsigned int x = __float_as_uint(f);
    unsigned int r = (x + 0x7FFFu + ((x >> 16) & 1u)) >> 16;
    return (unsigned short)r;
}
__device__ __forceinline__ float bf2f(unsigned short h) {
    return __uint_as_float(((unsigned int)h) << 16);
}
// 2-way bf16 split: w ~= h0+h1 (residual ~2^-17 rel)
__device__ __forceinline__ void split2(float w, unsigned short& h0,
                                       unsigned short& h1) {
    h0 = f2bf(w);          float r0 = w - bf2f(h0);
    h1 = f2bf(r0);
}
// HW fp8 converts
__device__ __forceinline__ unsigned char f2fp8(float f) {
    int pk = __builtin_amdgcn_cvt_pk_fp8_f32(f, 0.f, 0, false);
    return (unsigned char)(pk & 0xFF);
}
__device__ __forceinline__ float fp82f(unsigned char b) {
    return __builtin_amdgcn_cvt_f32_fp8((int)b, 0);
}

// ---------------------------------------------------------------------------
// prep_scan_pack: fused input prep + weight packing.
// Blocks 0..4991: row (b*156+c) of In [4992][2048]:
//   Infp8[row][t] = fp8(x)   (exact: x binary {0,1})
//   Pbf [row][t]  = bf16(psp_t(x))   (psp commutes with W1-dense)
// Blocks 4992..6079: weight packing:
//   W1 -> split-2 bf16; W2 -> split-2 fp8; Wl1 -> split-2 fp8 x64-scaled;
//   Wl2 -> split-2 bf16.
// ---------------------------------------------------------------------------
__global__ __launch_bounds__(256) void prep_scan_pack(
    const float* __restrict__ In, unsigned char* __restrict__ Infp8,
    unsigned short* __restrict__ Pbf,
    const float* __restrict__ W1,  const float* __restrict__ W2,
    const float* __restrict__ Wl1, const float* __restrict__ Wl2,
    unsigned short* __restrict__ W1p,  unsigned char* __restrict__ W2p8,
    unsigned char* __restrict__ Wl1p8, unsigned short* __restrict__ Wl2p)
{
    const int blk = blockIdx.x;
    if (blk >= 4992) {
        const int bidx = blk - 4992;
        if (bidx >= 512 && bidx < 544) {            // W2 -> fp8 split-2
            int m = bidx - 512;
            for (int k = threadIdx.x; k < 512; k += 256) {
                float w = (m < 20) ? W2[(long long)m * 512 + k] : 0.f;
                unsigned char h0 = f2fp8(w);
                unsigned char h1 = f2fp8(w - fp82f(h0));
                W2p8[(long long)m * 512 + k] = h0;
                W2p8[16384 + (long long)m * 512 + k] = h1;
            }
        } else if (bidx >= 544 && bidx < 1056) {    // Wl1 -> fp8 split-2, x64
            int m = bidx - 544;
            for (int k = threadIdx.x; k < 2048; k += 256) {
                float w = Wl1[(long long)m * 2048 + k] * 64.0f;
                unsigned char h0 = f2fp8(w);
                unsigned char h1 = f2fp8(w - fp82f(h0));
                Wl1p8[(long long)m * 2048 + k] = h0;
                Wl1p8[1048576 + (long long)m * 2048 + k] = h1;
            }
        } else {                                    // W1 / Wl2 -> bf16 split-2
            const float* W; unsigned short* P; int M, K, Kp, Mp, m;
            if (bidx < 512) { W = W1;  P = W1p;  M = 512; K = 156; Kp = 160; Mp = 512; m = bidx; }
            else            { W = Wl2; P = Wl2p; M = 20;  K = 512; Kp = 512; Mp = 32;  m = bidx - 1056; }
            for (int k = threadIdx.x; k < Kp; k += 256) {
                float v = (m < M && k < K) ? W[(long long)m * K + k] : 0.f;
                unsigned short h0, h1;
                split2(v, h0, h1);
                P[(long long)m * Kp + k] = h0;
                P[(long long)Mp * Kp + (long long)m * Kp + k] = h1;
            }
        }
        return;
    }

    const int row = blk;
    const int tid = threadIdx.x;
    const float* x = In + (long long)row * 2048 + tid * 8;
    const unsigned char ONE8 = f2fp8(1.0f);

    float v[8];
    *(f32x4v*)&v[0] = *(const f32x4v*)x;
    *(f32x4v*)&v[4] = *(const f32x4v*)(x + 4);

    uchar8v raw;
    #pragma unroll
    for (int k = 0; k < 8; ++k) raw[k] = (v[k] >= 0.5f) ? ONE8 : (unsigned char)0;
    *(uchar8v*)(Infp8 + (long long)row * 2048 + tid * 8) = raw;

    float y = 0.f;
    #pragma unroll
    for (int k = 0; k < 8; ++k) { y = ALPHA * y + v[k]; v[k] = y; }

    __shared__ float sc[256];
    float val = y;
    sc[tid] = val;
    float m = ALPHA8;
    for (int d = 1; d < 256; d <<= 1) {
        __syncthreads();
        float p = (tid >= d) ? sc[tid - d] : 0.f;
        __syncthreads();
        val += m * p;
        sc[tid] = val;
        m *= m;
    }
    __syncthreads();
    float carry = (tid > 0) ? sc[tid - 1] : 0.f;

    ushort8v pv;
    float ak = ALPHA;
    #pragma unroll
    for (int k = 0; k < 8; ++k) {
        float yk = v[k] + ak * carry;
        ak *= ALPHA;
        pv[k] = f2bf(yk);
    }
    *(ushort8v*)(Pbf + (long long)row * 2048 + tid * 8) = pv;
}

// ---------------------------------------------------------------------------
// transposeP: Pbf [32*156][2048] bf16 -> PT [32][2048][160] (c padded to 160).
// ---------------------------------------------------------------------------
__global__ __launch_bounds__(256) void transposeP(
    const unsigned short* __restrict__ Pbf, unsigned short* __restrict__ PT)
{
    __shared__ unsigned short Tile[64][72];
    const int t0 = blockIdx.x * 64;
    const int c0 = blockIdx.y * 64;
    const int b  = blockIdx.z;
    const int tid = threadIdx.x;

    #pragma unroll
    for (int s = 0; s < 2; ++s) {
        int id = tid + s * 256;
        int cc = id >> 3;
        int t8 = (id & 7) * 8;
        ushort8v v = {0,0,0,0,0,0,0,0};
        if (c0 + cc < 156)
            v = *(const ushort8v*)(Pbf + (long long)(b * 156 + c0 + cc) * 2048 + t0 + t8);
        *(ushort8v*)&Tile[cc][t8] = v;
    }
    __syncthreads();

    #pragma unroll
    for (int s = 0; s < 2; ++s) {
        int id = tid + s * 256;
        int t  = id >> 3;
        int c8 = (id & 7) * 8;
        if (c0 + c8 + 7 < 160) {
            unsigned short r[8];
            #pragma unroll
            for (int j = 0; j < 8; ++j) r[j] = Tile[c8 + j][t];
            *(ushort8v*)(PT + (long long)b * 327680 + (long long)(t0 + t) * 160 + c0 + c8)
                = *(ushort8v*)r;
        }
    }
}

// ---------------------------------------------------------------------------
// MEGA1: blocks [0,2048)  = branch-1 GEMM1 (bf16 MFMA, fused threshold,
//                           bit-packed spike output)
//        blocks [2048,3328) = branch-2 GEMM1 (fp8 MFMA, split-K x4), laid out
//                           n + 40*(m + 8*ks) to preserve XCD mod-8 reuse.
// ---------------------------------------------------------------------------
__global__ __launch_bounds__(256) void mega_gemm1(
    const unsigned short* __restrict__ W1p,
    const unsigned short* __restrict__ PT,
    unsigned short* __restrict__ S1bits,     // [32][512][128]
    const unsigned char* __restrict__ Wl1p8, // [2][512][2048] fp8
    const unsigned char* __restrict__ Infp8, // [4992][2048] fp8
    unsigned short* __restrict__ Zp)         // [4][156][16384] c-major bf16
{
    __shared__ alignas(16) unsigned char SMEM[30720];
    const int bx  = blockIdx.x;
    const int tid = threadIdx.x;
    const int lane = tid & 63, w = tid >> 6;
    const int wy = w >> 1, wx = w & 1;
    const int l15 = lane & 15, kq = lane >> 4;

    if (bx < 2048) {
        // ================= branch-1 GEMM1 =================
        auto As = (unsigned short (*)[128][40])SMEM;       // [2][128][40]
        auto Bs = (unsigned short (*)[40])(SMEM + 20480);  // [128][40]

        const int z  = bx >> 6;
        const int m0 = ((bx >> 4) & 3) * 128;
        const int n0 = (bx & 15) * 128;
        const unsigned short* Tb = PT + (long long)z * 327680;

        int aPl[4], aM[4], aK8[4];
        #pragma unroll
        for (int s = 0; s < 4; ++s) {
            int id = tid + s * 256;
            aPl[s] = id >> 9; int rem = id & 511;
            aM[s] = rem >> 2; aK8[s] = (rem & 3) * 8;
        }
        int bT[2], bC8[2];
        #pragma unroll
        for (int s = 0; s < 2; ++s) {
            int id = tid + s * 256;
            bT[s] = id >> 2; bC8[s] = (id & 3) * 8;
        }

        f32x4 acc[4][4] = {};
        ushort8v aReg[4], bReg[2];

        #pragma unroll
        for (int s = 0; s < 4; ++s)
            aReg[s] = *(const ushort8v*)(W1p + (long long)aPl[s] * 81920 +
                                         (long long)(m0 + aM[s]) * 160 + aK8[s]);
        #pragma unroll
        for (int s = 0; s < 2; ++s)
            bReg[s] = *(const ushort8v*)(Tb + (long long)(n0 + bT[s]) * 160 + bC8[s]);
        #pragma unroll
        for (int s = 0; s < 4; ++s) *(ushort8v*)&As[aPl[s]][aM[s]][aK8[s]] = aReg[s];
        #pragma unroll
        for (int s = 0; s < 2; ++s) *(ushort8v*)&Bs[bT[s]][bC8[s]] = bReg[s];
        __syncthreads();

        #pragma unroll
        for (int it = 0; it < 5; ++it) {
            const int kn = (it + 1) * 32;
            if (it < 4) {
                #pragma unroll
                for (int s = 0; s < 4; ++s)
                    aReg[s] = *(const ushort8v*)(W1p + (long long)aPl[s] * 81920 +
                                                 (long long)(m0 + aM[s]) * 160 + kn + aK8[s]);
                #pragma unroll
                for (int s = 0; s < 2; ++s)
                    bReg[s] = *(const ushort8v*)(Tb + (long long)(n0 + bT[s]) * 160 + kn + bC8[s]);
            }

            bf16x8 bfr[4];
            #pragma unroll
            for (int nt = 0; nt < 4; ++nt)
                bfr[nt] = *(const bf16x8*)&Bs[wx * 64 + nt * 16 + l15][kq * 8];
            #pragma unroll
            for (int s = 0; s < 2; ++s) {
                #pragma unroll
                for (int mt = 0; mt < 4; ++mt) {
                    bf16x8 afr = *(const bf16x8*)&As[s][wy * 64 + mt * 16 + l15][kq * 8];
                    #pragma unroll
                    for (int nt = 0; nt < 4; ++nt)
                        acc[mt][nt] = __builtin_amdgcn_mfma_f32_16x16x32_bf16(
                            afr, bfr[nt], acc[mt][nt], 0, 0, 0);
                }
            }
            __syncthreads();
            if (it < 4) {
                #pragma unroll
                for (int s = 0; s < 4; ++s) *(ushort8v*)&As[aPl[s]][aM[s]][aK8[s]] = aReg[s];
                #pragma unroll
                for (int s = 0; s < 2; ++s) *(ushort8v*)&Bs[bT[s]][bC8[s]] = bReg[s];
                __syncthreads();
            }
        }

        unsigned short* Db = S1bits + (long long)z * 512 * 128;
        #pragma unroll
        for (int mt = 0; mt < 4; ++mt) {
            #pragma unroll
            for (int i = 0; i < 4; ++i) {
                int m = m0 + wy * 64 + mt * 16 + kq * 4 + i;
                #pragma unroll
                for (int nt = 0; nt < 4; ++nt) {
                    unsigned long long mask = __ballot(acc[mt][nt][i] >= THETA);
                    if (l15 == 0) {
                        int nchunk = (n0 + wx * 64 + nt * 16) >> 4;
                        Db[(long long)m * 128 + nchunk] =
                            (unsigned short)((mask >> (kq * 16)) & 0xFFFFu);
                    }
                }
            }
        }
    } else {
        // ================= branch-2 GEMM1 (fp8) =================
        auto As8 = (unsigned char (*)[64][72])SMEM;        // [2][64][72]
        auto Bs8 = (unsigned char (*)[72])(SMEM + 9216);   // [128][72]

        const int id0 = bx - 2048;
        const int nIdx = id0 % 40;
        if (nIdx >= 39) return;
        const int rest = id0 / 40;
        const int n0  = nIdx * 128;
        const int m0  = (rest & 7) * 64;
        const int ksl = rest >> 3;
        const int ks0 = ksl * 512;

        int aPl[4], aM[4], aK8[4];
        #pragma unroll
        for (int s = 0; s < 4; ++s) {
            int id = tid + s * 256;
            aPl[s] = id >> 9; int rem = id & 511;
            aM[s] = rem >> 3; aK8[s] = (rem & 7) * 8;
        }
        int bN[4], bK8[4];
        #pragma unroll
        for (int s = 0; s < 4; ++s) {
            int id = tid + s * 256;
            bN[s] = id >> 3; bK8[s] = (id & 7) * 8;
        }

        f32x4 acc[2][4] = {};
        uchar8v aReg[4], bReg[4];

        #pragma unroll
        for (int s = 0; s < 4; ++s)
            aReg[s] = *(const uchar8v*)(Wl1p8 + (long long)aPl[s] * 1048576 +
                                        (long long)(m0 + aM[s]) * 2048 + ks0 + aK8[s]);
        #pragma unroll
        for (int s = 0; s < 4; ++s)
            bReg[s] = *(const uchar8v*)(Infp8 + (long long)(n0 + bN[s]) * 2048 + ks0 + bK8[s]);
        #pragma unroll
        for (int s = 0; s < 4; ++s) *(uchar8v*)&As8[aPl[s]][aM[s]][aK8[s]] = aReg[s];
        #pragma unroll
        for (int s = 0; s < 4; ++s) *(uchar8v*)&Bs8[bN[s]][bK8[s]] = bReg[s];
        __syncthreads();

        for (int it = 0; it < 8; ++it) {
            const int kn = ks0 + (it + 1) * 64;
            if (it < 7) {
                #pragma unroll
                for (int s = 0; s < 4; ++s)
                    aReg[s] = *(const uchar8v*)(Wl1p8 + (long long)aPl[s] * 1048576 +
                                                (long long)(m0 + aM[s]) * 2048 + kn + aK8[s]);
                #pragma unroll
                for (int s = 0; s < 4; ++s)
                    bReg[s] = *(const uchar8v*)(Infp8 + (long long)(n0 + bN[s]) * 2048 + kn + bK8[s]);
            }

            #pragma unroll
            for (int ks = 0; ks < 2; ++ks) {
                i64 bfr[4];
                #pragma unroll
                for (int nt = 0; nt < 4; ++nt)
                    bfr[nt] = *(const i64*)&Bs8[wx * 64 + nt * 16 + l15][ks * 32 + kq * 8];
                #pragma unroll
                for (int s = 0; s < 2; ++s) {
                    #pragma unroll
                    for (int mt = 0; mt < 2; ++mt) {
                        i64 afr = *(const i64*)&As8[s][wy * 32 + mt * 16 + l15][ks * 32 + kq * 8];
                        #pragma unroll
                        for (int nt = 0; nt < 4; ++nt)
                            acc[mt][nt] = __builtin_amdgcn_mfma_f32_16x16x32_fp8_fp8(
                                afr, bfr[nt], acc[mt][nt], 0, 0, 0);
                    }
                }
            }
            __syncthreads();
            if (it < 7) {
                #pragma unroll
                for (int s = 0; s < 4; ++s) *(uchar8v*)&As8[aPl[s]][aM[s]][aK8[s]] = aReg[s];
                #pragma unroll
                for (int s = 0; s < 4; ++s) *(uchar8v*)&Bs8[bN[s]][bK8[s]] = bReg[s];
                __syncthreads();
            }
        }

        unsigned short* Tu = (unsigned short*)SMEM;
        #pragma unroll
        for (int mt = 0; mt < 2; ++mt) {
            #pragma unroll
            for (int i = 0; i < 4; ++i) {
                int mL = wy * 32 + mt * 16 + kq * 4 + i;
                #pragma unroll
                for (int nt = 0; nt < 4; ++nt) {
                    int nL = wx * 64 + nt * 16 + l15;
                    Tu[mL * 129 + nL] = f2bf(acc[mt][nt][i] * ISCALE);
                }
            }
        }
        __syncthreads();

        unsigned short* Zs = Zp + (long long)ksl * 2555904;
        #pragma unroll
        for (int s2 = 0; s2 < 32; ++s2) {
            int id = tid + s2 * 256;
            int cL = id >> 6;
            int mL = id & 63;
            int n = n0 + cL;
            int bb = n / 156, cc = n - bb * 156;
            Zs[(long long)cc * 16384 + bb * 512 + m0 + mL] = Tu[mL * 129 + cL];
        }
    }
}

// ---------------------------------------------------------------------------
// MEGA2: blocks [0,1024)    = branch-1 GEMM2 (fp8 MFMA, split-K x2, bit-
//                             expanded B)
//        blocks [1024,1536) = branch-2 scan_sum4_perm (32 rows/block)
// ---------------------------------------------------------------------------
__global__ __launch_bounds__(256) void mega_stage2(
    const unsigned char* __restrict__ W2p8,
    const unsigned short* __restrict__ S1bits,
    float* __restrict__ C2p,
    const unsigned short* __restrict__ Zp,
    const int* __restrict__ perm,
    unsigned short* __restrict__ L1T)
{
    __shared__ alignas(16) unsigned char SMEM[20608];
    const int bx  = blockIdx.x;
    const int tid = threadIdx.x;

    if (bx < 1024) {
        auto As = (unsigned char (*)[32][72])SMEM;        // [2][32][72]
        auto Bs = (unsigned char (*)[72])(SMEM + 4608);   // [128][72]

        const int lane = tid & 63, w = tid >> 6;
        const int l15 = lane & 15, kq = lane >> 4;
        const int n0  = (bx & 15) * 128;
        const int ksl = (bx >> 4) & 1;
        const int b   = bx >> 5;
        const int ks0 = ksl * 256;

        const unsigned short* Bb = S1bits + (long long)b * 512 * 128;
        const unsigned char ONE8 = f2fp8(1.0f);

        int aPl[2], aM[2], aK8[2];
        #pragma unroll
        for (int s = 0; s < 2; ++s) {
            int id = tid + s * 256;
            aPl[s] = id >> 8; int rem = id & 255;
            aM[s] = rem >> 3; aK8[s] = (rem & 7) * 8;
        }
        const int kb = (tid >> 4) * 4;
        const int nb = (tid & 15) * 8;
        const int nchunk = (n0 + nb) >> 4;
        const int nshift = nb & 15;

        f32x4 acc[2][2] = {};
        uchar8v aReg[2];
        unsigned short bBits[4];

        auto loadA = [&](int k0) {
            #pragma unroll
            for (int s = 0; s < 2; ++s)
                aReg[s] = *(const uchar8v*)(W2p8 + (long long)aPl[s] * 16384 +
                                            (long long)aM[s] * 512 + k0 + aK8[s]);
        };
        auto loadB = [&](int k0) {
            #pragma unroll
            for (int kk2 = 0; kk2 < 4; ++kk2)
                bBits[kk2] = Bb[(long long)(k0 + kb + kk2) * 128 + nchunk];
        };
        auto stage = [&]() {
            #pragma unroll
            for (int s = 0; s < 2; ++s) *(uchar8v*)&As[aPl[s]][aM[s]][aK8[s]] = aReg[s];
            unsigned char bv[4][8];
            #pragma unroll
            for (int kk2 = 0; kk2 < 4; ++kk2) {
                unsigned int bits = ((unsigned int)bBits[kk2] >> nshift) & 0xFFu;
                #pragma unroll
                for (int j = 0; j < 8; ++j)
                    bv[kk2][j] = ((bits >> j) & 1u) ? ONE8 : (unsigned char)0;
            }
            #pragma unroll
            for (int j = 0; j < 8; ++j) {
                uchar4v v4 = { bv[0][j], bv[1][j], bv[2][j], bv[3][j] };
                *(uchar4v*)&Bs[nb + j][kb] = v4;
            }
        };

        loadA(ks0); loadB(ks0);
        stage();
        __syncthreads();

        #pragma unroll
        for (int it = 0; it < 4; ++it) {
            const int kn = ks0 + (it + 1) * 64;
            if (it < 3) { loadA(kn); loadB(kn); }

            #pragma unroll
            for (int ks = 0; ks < 2; ++ks) {
                i64 bfr[2];
                #pragma unroll
                for (int nt = 0; nt < 2; ++nt)
                    bfr[nt] = *(const i64*)&Bs[w * 32 + nt * 16 + l15][ks * 32 + kq * 8];
                #pragma unroll
                for (int s = 0; s < 2; ++s) {
                    #pragma unroll
                    for (int mt = 0; mt < 2; ++mt) {
                        i64 afr = *(const i64*)&As[s][mt * 16 + l15][ks * 32 + kq * 8];
                        #pragma unroll
                        for (int nt = 0; nt < 2; ++nt)
                            acc[mt][nt] = __builtin_amdgcn_mfma_f32_16x16x32_fp8_fp8(
                                afr, bfr[nt], acc[mt][nt], 0, 0, 0);
                    }
                }
            }
            __syncthreads();
            if (it < 3) {
                stage();
                __syncthreads();
            }
        }

        float* Cb = C2p + (long long)b * 20 * 2048 + (long long)ksl * 1310720LL;
        #pragma unroll
        for (int mt = 0; mt < 2; ++mt) {
            #pragma unroll
            for (int i = 0; i < 4; ++i) {
                int m = mt * 16 + kq * 4 + i;
                if (m >= 20) continue;
                #pragma unroll
                for (int nt = 0; nt < 2; ++nt) {
                    int n = n0 + w * 32 + nt * 16 + l15;
                    Cb[(long long)m * 2048 + n] = acc[mt][nt][i];
                }
            }
        }
    } else {
        auto Xs = (float (*)[32])SMEM;              // [156][32]
        int* p  = (int*)(SMEM + 19968);             // [156]

        const int r0 = (bx - 1024) * 32;
        for (int i = tid; i < 156; i += 256) p[i] = perm[i];

        const int row = tid & 31;
        const int cq  = tid >> 5;
        #pragma unroll
        for (int it = 0; it < 20; ++it) {
            int c = it * 8 + cq;
            if (c < 156) {
                long long base = (long long)c * 16384 + r0 + row;
                float s = bf2f(Zp[base]) + bf2f(Zp[base + 2555904]) +
                          bf2f(Zp[base + 2 * 2555904]) + bf2f(Zp[base + 3 * 2555904]);
                Xs[c][row] = s;
            }
        }
        __syncthreads();

        if (tid < 32) {
            float y = 0.f;
            for (int c = 0; c < 156; ++c) {
                y = ALPHA * y + Xs[p[c]][tid];
                L1T[(long long)c * 16384 + r0 + tid] = (y >= THETA) ? BF1 : 0;
            }
        }
    }
}

// ---------------------------------------------------------------------------
// MEGA3: blocks [0,640)   = branch-1 final T-scan (sum 2 partials -> spikes)
//        blocks [640,704) = branch-2 GEMM2 (bf16 MFMA)
// ---------------------------------------------------------------------------
__global__ __launch_bounds__(256) void mega_stage3(
    const float* __restrict__ C2p, float* __restrict__ out,
    const unsigned short* __restrict__ Wl2p,
    const unsigned short* __restrict__ L1T,
    float* __restrict__ Cl2)
{
    __shared__ alignas(16) unsigned char SMEM[27648];
    const int bx  = blockIdx.x;
    const int tid = threadIdx.x;

    if (bx < 640) {
        float* sc = (float*)SMEM;
        const int row = bx;
        const float* x = C2p + (long long)row * 2048 + tid * 8;

        float v[8];
        #pragma unroll
        for (int k = 0; k < 8; ++k) v[k] = x[k] + x[k + 1310720LL];

        float y = 0.f;
        #pragma unroll
        for (int k = 0; k < 8; ++k) { y = ALPHA * y + v[k]; v[k] = y; }

        float val = y;
        sc[tid] = val;
        float m = ALPHA8;
        for (int d = 1; d < 256; d <<= 1) {
            __syncthreads();
            float p = (tid >= d) ? sc[tid - d] : 0.f;
            __syncthreads();
            val += m * p;
            sc[tid] = val;
            m *= m;
        }
        __syncthreads();
        float carry = (tid > 0) ? sc[tid - 1] : 0.f;

        float* o = out + (long long)row * 2204 + tid * 8;
        float ak = ALPHA;
        #pragma unroll
        for (int k = 0; k < 8; ++k) {
            float yk = v[k] + ak * carry;
            ak *= ALPHA;
            o[k] = (yk >= THETA) ? 1.0f : 0.0f;
        }
    } else {
        auto As = (unsigned short (*)[32][72])SMEM;         // [2][32][72]
        auto Bs = (unsigned short (*)[72])(SMEM + 9216);    // [128][72]

        const int id2 = bx - 640;
        const int n0 = (id2 & 1) * 128;
        const int b  = id2 >> 1;
        const int lane = tid & 63, w = tid >> 6;
        const int l15 = lane & 15, kq = lane >> 4;

        f32x4 acc[2][2] = {};

        for (int k0 = 0; k0 < 512; k0 += 64) {
            #pragma unroll
            for (int s = 0; s < 2; ++s) {
                int id = tid + s * 256;
                int pl = id >> 8, rem = id & 255;
                int m = rem >> 3, k8 = (rem & 7) * 8;
                ushort8v v = *(const ushort8v*)(Wl2p + (long long)pl * 16384 +
                                                (long long)m * 512 + k0 + k8);
                *(ushort8v*)&As[pl][m][k8] = v;
            }
            #pragma unroll
            for (int s = 0; s < 4; ++s) {
                int id = tid + s * 256;
                int n = id >> 3, k8 = (id & 7) * 8;
                ushort8v v = {0,0,0,0,0,0,0,0};
                if (n0 + n < 156)
                    v = *(const ushort8v*)(L1T + (long long)(n0 + n) * 16384 +
                                           b * 512 + k0 + k8);
                *(ushort8v*)&Bs[n][k8] = v;
            }
            __syncthreads();

            #pragma unroll
            for (int ks = 0; ks < 2; ++ks) {
                bf16x8 bfr[2];
                #pragma unroll
                for (int nt = 0; nt < 2; ++nt)
                    bfr[nt] = *(const bf16x8*)&Bs[w * 32 + nt * 16 + l15][ks * 32 + kq * 8];
                #pragma unroll
                for (int s = 0; s < 2; ++s) {
                    #pragma unroll
                    for (int mt = 0; mt < 2; ++mt) {
                        bf16x8 afr = *(const bf16x8*)&As[s][mt * 16 + l15][ks * 32 + kq * 8];
                        #pragma unroll
                        for (int nt = 0; nt < 2; ++nt)
                            acc[mt][nt] = __builtin_amdgcn_mfma_f32_16x16x32_bf16(
                                afr, bfr[nt], acc[mt][nt], 0, 0, 0);
                    }
                }
            }
            __syncthreads();
        }

        float* Cb = Cl2 + (long long)b * 20 * 156;
        #pragma unroll
        for (int mt = 0; mt < 2; ++mt) {
            #pragma unroll
            for (int i = 0; i < 4; ++i) {
                int m = mt * 16 + kq * 4 + i;
                if (m >= 20) continue;
                #pragma unroll
                for (int nt = 0; nt < 2; ++nt) {
                    int n = n0 + w * 32 + nt * 16 + l15;
                    if (n < 156) Cb[(long long)m * 156 + n] = acc[mt][nt][i];
                }
            }
        }
    }
}

// ---------------------------------------------------------------------------
// Final branch-2 output scan (length 156 per row, 640 rows).
// ---------------------------------------------------------------------------
__global__ __launch_bounds__(256) void scan_spike_C_out(
    const float* __restrict__ in, float* __restrict__ out, int rows)
{
    int row = blockIdx.x * blockDim.x + threadIdx.x;
    if (row >= rows) return;
    const float* x = in + (long long)row * 156;
    float* o = out + (long long)row * 2204 + 2048;
    float y = 0.f;
    for (int c = 0; c < 156; ++c) {
        y = ALPHA * y + x[c];
        o[c] = (y >= THETA) ? 1.0f : 0.0f;
    }
}

// ---------------------------------------------------------------------------
// B=32, C_IN=156, T=2048, HID=512, OUT=20. Output [32,20,2204].
// ---------------------------------------------------------------------------
extern "C" void kernel_launch(void* const* d_in, const int* in_sizes, int n_in,
                              void* d_out, int out_size, void* d_ws, size_t ws_size,
                              hipStream_t stream)
{
    const float* In  = (const float*)d_in[0];  // [32][156][2048]
    const float* W1  = (const float*)d_in[1];  // [512][156]
    const float* W2  = (const float*)d_in[2];  // [20][512]
    const float* Wl1 = (const float*)d_in[3];  // [512][2048]
    const float* Wl2 = (const float*)d_in[4];  // [20][512]
    const int*  perm = (const int*)d_in[5];    // [156]
    float* out = (float*)d_out;                // [32][20][2204]

    float* ws = (float*)d_ws;
    // Disjoint layout (float offsets; ws is 256 MiB):
    unsigned short* S1bits = (unsigned short*)ws;              // [32][512][128]
    float* C2p = ws + 1048576LL;                               // [2][32][20][2048]
    unsigned char*  Infp8 = (unsigned char*)(ws + 3670016LL);  // [4992][2048] fp8
    unsigned short* Pbf  = (unsigned short*)(ws + 6225920LL);  // [4992][2048]
    unsigned short* PT   = (unsigned short*)(ws + 11337728LL); // [32][2048][160]
    unsigned short* W1p  = (unsigned short*)(ws + 16580608LL); // [2][512][160]
    unsigned char*  W2p8 = (unsigned char*)(ws + 16662528LL);  // [2][32][512] fp8
    unsigned char*  Wl1p8= (unsigned char*)(ws + 16670720LL);  // [2][512][2048] fp8
    unsigned short* Wl2p = (unsigned short*)(ws + 17195008LL); // [2][32][512]
    unsigned short* Zpbf = (unsigned short*)(ws + 17211392LL); // [4][156][16384] bf16
    unsigned short* L1T  = (unsigned short*)(ws + 22323200LL); // [156][16384]
    float* Cl2 = ws + 23601152LL;                              // [32][20][156]

    dim3 blk(256);

    // ---- Preprocess (fused scan + pack) ----
    prep_scan_pack<<<dim3(6080), blk, 0, stream>>>(
        In, Infp8, Pbf, W1, W2, Wl1, Wl2, W1p, W2p8, Wl1p8, Wl2p);
    transposeP<<<dim3(32, 3, 32), blk, 0, stream>>>(Pbf, PT);

    // ---- Stage 1: both branch GEMM1s in one launch ----
    mega_gemm1<<<dim3(3328), blk, 0, stream>>>(W1p, PT, S1bits,
                                               Wl1p8, Infp8, Zpbf);
    // ---- Stage 2: branch-1 GEMM2 + branch-2 perm-scan ----
    mega_stage2<<<dim3(1536), blk, 0, stream>>>(W2p8, S1bits, C2p,
                                                Zpbf, perm, L1T);
    // ---- Stage 3: branch-1 final scan + branch-2 GEMM2 ----
    mega_stage3<<<dim3(704), blk, 0, stream>>>(C2p, out, Wl2p, L1T, Cl2);
    // ---- Branch-2 output scan ----
    scan_spike_C_out<<<dim3(3), blk, 0, stream>>>(Cl2, out, 640);

    (void)in_sizes; (void)n_in; (void)out_size; (void)ws_size;
}